// Round 2
// baseline (321.143 us; speedup 1.0000x reference)
//
#include <hip/hip_runtime.h>
#include <hip/hip_bf16.h>

typedef __attribute__((ext_vector_type(8))) short s16x8;
typedef __attribute__((ext_vector_type(4))) float f32x4;
typedef __attribute__((ext_vector_type(4))) unsigned short us4;
typedef __attribute__((ext_vector_type(4))) unsigned int u32x4;

#define MFMA16(a,b,c) __builtin_amdgcn_mfma_f32_16x16x32_bf16((a),(b),(c),0,0,0)

__device__ __forceinline__ unsigned short f2b(float f){
  union{float f; unsigned u;} v; v.f = f;
  unsigned r = v.u + 0x7fffu + ((v.u>>16)&1u);
  return (unsigned short)(r>>16);
}

__device__ __forceinline__ void gl_lds16(const void* gp, void* lp){
  __builtin_amdgcn_global_load_lds((const __attribute__((address_space(1))) void*)gp,
                                   (__attribute__((address_space(3))) void*)lp, 16, 0, 0);
}

// stage 64 rows x 256 cols bf16 (row stride `stride` elems) with XOR swizzle ((row&7)<<4)
__device__ __forceinline__ void stage_64x256(void* lds, const unsigned short* g, int stride){
  const int t = threadIdx.x, wv = t>>6;
  #pragma unroll
  for (int i=0;i<8;++i){
    int ch = i*256 + t;
    int row = ch>>5, cc = ch&31, sc = cc ^ (row&7);
    gl_lds16((const char*)(g + (size_t)row*stride) + sc*16,
             (char*)lds + (((size_t)i*256 + wv*64)<<4));
  }
}
// stage 256 rows x 64 cols bf16 (row stride 4096 elems) with XOR swizzle ((row&7)<<4)
__device__ __forceinline__ void stage_256x64(void* lds, const unsigned short* g){
  const int t = threadIdx.x, wv = t>>6;
  #pragma unroll
  for (int i=0;i<8;++i){
    int ch = i*256 + t;
    int row = ch>>3, cc = ch&7, sc = cc ^ (row&7);
    gl_lds16((const char*)(g + (size_t)row*4096) + sc*16,
             (char*)lds + (((size_t)i*256 + wv*64)<<4));
  }
}

// ---------------- f32 -> bf16 cast ----------------
__global__ void k_cvt(const float* __restrict__ src, unsigned short* __restrict__ dst){
  int i = blockIdx.x*256 + threadIdx.x;
  f32x4 v = *(const f32x4*)(src + (size_t)i*4);
  us4 o;
  #pragma unroll
  for (int r=0;r<4;++r) o[r] = f2b(v[r]);
  *(us4*)(dst + (size_t)i*4) = o;
}

// ---------------- density chain (all f32) ----------------
__global__ void k_gray(const float* __restrict__ xg, float* __restrict__ gray){
  int b = blockIdx.y, n = blockIdx.x*256 + threadIdx.x;
  const float* p = xg + (size_t)b*256*4096 + n;
  float s0=0,s1=0,s2=0,s3=0;
  for (int c=0;c<256;c+=4){
    s0 += p[(size_t)c*4096];
    s1 += p[(size_t)(c+1)*4096];
    s2 += p[(size_t)(c+2)*4096];
    s3 += p[(size_t)(c+3)*4096];
  }
  gray[b*4096+n] = (s0+s1+s2+s3)*(1.f/256.f);
}

__global__ void k_lapabs(const float* __restrict__ gray, float* __restrict__ labs){
  int b = blockIdx.y, n = blockIdx.x*256 + threadIdx.x;
  int hh = n>>6, ww = n&63;
  const float* g = gray + b*4096;
  float c = g[n];
  float up = hh>0  ? g[n-64] : 0.f;
  float dn = hh<63 ? g[n+64] : 0.f;
  float lf = ww>0  ? g[n-1]  : 0.f;
  float rt = ww<63 ? g[n+1]  : 0.f;
  labs[b*4096+n] = fabsf(4.f*c - up - dn - lf - rt);
}

__global__ void k_h8(const float* __restrict__ labs, const float* __restrict__ w1,
                     const float* __restrict__ b1, float* __restrict__ hbuf){
  int b = blockIdx.y, n = blockIdx.x*256 + threadIdx.x;
  int hh = n>>6, ww = n&63;
  const float* L = labs + b*4096;
  float tap[9];
  #pragma unroll
  for (int dy=-1;dy<=1;++dy)
    #pragma unroll
    for (int dx=-1;dx<=1;++dx){
      int y=hh+dy, x2=ww+dx;
      tap[(dy+1)*3+dx+1] = (y>=0&&y<64&&x2>=0&&x2<64)? L[y*64+x2] : 0.f;
    }
  #pragma unroll
  for (int j=0;j<8;++j){
    float a = b1[j];
    #pragma unroll
    for (int k=0;k<9;++k) a += w1[j*9+k]*tap[k];
    hbuf[((size_t)(b*8+j))*4096 + n] = fmaxf(a, 0.f);
  }
}

__global__ void k_scale(const float* __restrict__ hbuf, const float* __restrict__ w2,
                        const float* __restrict__ b2_, float* __restrict__ sc){
  int b = blockIdx.y, n = blockIdx.x*256 + threadIdx.x;
  int hh = n>>6, ww = n&63;
  float a = b2_[0];
  #pragma unroll
  for (int j=0;j<8;++j){
    const float* H = hbuf + ((size_t)(b*8+j))*4096;
    #pragma unroll
    for (int dy=-1;dy<=1;++dy)
      #pragma unroll
      for (int dx=-1;dx<=1;++dx){
        int y=hh+dy, x2=ww+dx;
        if (y>=0&&y<64&&x2>=0&&x2<64) a += w2[j*9+(dy+1)*3+(dx+1)]*H[y*64+x2];
      }
  }
  float sig = 1.f/(1.f+__expf(-a));
  sc[b*4096+n] = 0.0625f/(3.f - 2.f*sig);   // C^-0.5 / (1 + 2*(1-sig))
}

// ---------------- transpose+cast x[b][c][n] (f32) -> Xt[b][n][c] (bf16) ----------------
__global__ void k_transpose(const float* __restrict__ xg, unsigned short* __restrict__ Xtg){
  __shared__ unsigned short T[64*68];
  const int nb = blockIdx.x, cb = blockIdx.y, b = blockIdx.z;
  const int n0 = nb*64, c0 = cb*64;
  const int t = threadIdx.x;
  #pragma unroll
  for (int i=0;i<4;++i){
    int idx = i*256 + t;           // 1024 chunks of 4 f32
    int c = idx>>4, k4 = idx&15;
    f32x4 v = *(const f32x4*)(xg + ((size_t)(b*256 + c0 + c))*4096 + n0 + k4*4);
    us4 o;
    #pragma unroll
    for (int r=0;r<4;++r) o[r] = f2b(v[r]);
    *(us4*)&T[c*68 + k4*4] = o;
  }
  __syncthreads();
  #pragma unroll
  for (int i=0;i<2;++i){
    int idx = i*256 + t;
    int n = idx>>3, ck = idx&7;
    unsigned short vv[8];
    #pragma unroll
    for (int j=0;j<8;++j) vv[j] = T[(ck*8+j)*68 + n];
    *(u32x4*)(Xtg + ((size_t)(b*4096 + n0 + n))*256 + c0 + ck*8) = *(const u32x4*)vv;
  }
}

// ---------------- QKV GEMM: D[o][n] = qkv_w[o][c] * Xt[n][c]^T ----------------
__global__ __launch_bounds__(256,2) void k_gemm_qkv(const unsigned short* __restrict__ Wg,
    const unsigned short* __restrict__ Xtg, const float* __restrict__ biasg,
    unsigned short* __restrict__ Qo, unsigned short* __restrict__ Ko, unsigned short* __restrict__ Vto){
  __shared__ unsigned short Wl[64*256], Xl[64*256];
  const int nt_ = blockIdx.x, at = blockIdx.y, b = blockIdx.z;
  const int a0 = at*64, n0 = nt_*64;
  stage_64x256(Wl, Wg + (size_t)a0*256, 256);
  stage_64x256(Xl, Xtg + ((size_t)(b*4096 + n0))*256, 256);
  __syncthreads();
  const int t = threadIdx.x, w = t>>6, lane = t&63, lam = lane&15, lg = lane>>4;
  f32x4 zz = {0.f,0.f,0.f,0.f};
  f32x4 acc[4] = {zz,zz,zz,zz};
  #pragma unroll
  for (int u=0;u<8;++u){
    int ar = 16*w + lam;
    s16x8 af = *(const s16x8*)((const char*)Wl + ar*512 + ((64*u+16*lg) ^ ((ar&7)<<4)));
    #pragma unroll
    for (int ct=0;ct<4;++ct){
      int br = 16*ct + lam;
      s16x8 bf = *(const s16x8*)((const char*)Xl + br*512 + ((64*u+16*lg) ^ ((br&7)<<4)));
      acc[ct] = MFMA16(af, bf, acc[ct]);
    }
  }
  const int ob = a0 + 16*w + 4*lg;
  f32x4 bias4 = *(const f32x4*)(biasg + ob);
  #pragma unroll
  for (int ct=0;ct<4;++ct){
    int n = n0 + 16*ct + lam;
    us4 ov;
    #pragma unroll
    for (int r=0;r<4;++r) ov[r] = f2b(acc[ct][r] + bias4[r]);
    if (a0 < 256){
      *(us4*)(Qo + ((size_t)(b*4096 + n))*256 + ob) = ov;        // Q[n][c]
    } else if (a0 < 512){
      *(us4*)(Ko + ((size_t)(b*4096 + n))*256 + (ob-256)) = ov;  // K[m][c]
    } else {
      #pragma unroll
      for (int r=0;r<4;++r)
        Vto[((size_t)(b*256 + (ob-512+r)))*4096 + n] = ov[r];    // Vt[c][m]
    }
  }
}

// ---------------- flash attention ----------------
__global__ __launch_bounds__(256,2) void k_attn(const unsigned short* __restrict__ Qg,
    const unsigned short* __restrict__ Kg, const unsigned short* __restrict__ Vtg,
    const float* __restrict__ Sg, unsigned short* __restrict__ AOt){
  __shared__ unsigned short Kl[64*256];
  __shared__ unsigned short Vl[256*64];
  __shared__ float sl[64];
  __shared__ __align__(16) char Pl[4][16*144];

  const int t = threadIdx.x, w = t>>6, lane = t&63, lam = lane&15, lg = lane>>4;
  const int b = blockIdx.x>>6, qt = blockIdx.x&63;
  const int qbase = qt*64 + w*16;

  s16x8 qf[8];
  {
    const unsigned short* qp = Qg + ((size_t)(b*4096 + qbase + lam))*256 + lg*8;
    #pragma unroll
    for (int u=0;u<8;++u) qf[u] = *(const s16x8*)(qp + 32*u);
  }
  f32x4 zz = {0.f,0.f,0.f,0.f};
  f32x4 oa[16];
  #pragma unroll
  for (int i=0;i<16;++i) oa[i] = zz;
  float m_run = -1.0e30f, l_run = 0.f;

  for (int kt=0; kt<64; ++kt){
    const int m0 = kt*64;
    if (kt) __syncthreads();
    stage_64x256(Kl, Kg + ((size_t)(b*4096 + m0))*256, 256);
    stage_256x64(Vl, Vtg + (size_t)b*256*4096 + m0);
    if (t < 64) sl[t] = Sg[(size_t)b*4096 + m0 + t];
    __syncthreads();

    // S^T = K * Q^T  -> lane owns q-row lam, keys {16mt+4lg+r}
    f32x4 st[4] = {zz,zz,zz,zz};
    #pragma unroll
    for (int u=0;u<8;++u){
      #pragma unroll
      for (int mt=0;mt<4;++mt){
        int krow = 16*mt + lam;
        s16x8 kf = *(const s16x8*)((const char*)Kl + krow*512 + ((64*u + 16*lg) ^ ((krow&7)<<4)));
        st[mt] = MFMA16(kf, qf[u], st[mt]);
      }
    }
    // per-key scale + online softmax
    float p[4][4]; float tmax = -1.0e30f;
    #pragma unroll
    for (int mt=0;mt<4;++mt){
      f32x4 s4 = *(const f32x4*)&sl[16*mt + 4*lg];
      #pragma unroll
      for (int r=0;r<4;++r){ p[mt][r] = st[mt][r]*s4[r]; tmax = fmaxf(tmax, p[mt][r]); }
    }
    tmax = fmaxf(tmax, __shfl_xor(tmax, 16));
    tmax = fmaxf(tmax, __shfl_xor(tmax, 32));
    float mnew = fmaxf(m_run, tmax);
    float fs = __expf(m_run - mnew);
    float rsum = 0.f;
    #pragma unroll
    for (int mt=0;mt<4;++mt){
      #pragma unroll
      for (int r=0;r<4;++r){ float e = __expf(p[mt][r]-mnew); p[mt][r]=e; rsum += e; }
    }
    rsum += __shfl_xor(rsum, 16);
    rsum += __shfl_xor(rsum, 32);
    l_run = l_run*fs + rsum; m_run = mnew;
    // P -> per-wave LDS (row stride 144B, 16B-aligned)
    #pragma unroll
    for (int mt=0;mt<4;++mt){
      us4 pk;
      #pragma unroll
      for (int r=0;r<4;++r) pk[r] = f2b(p[mt][r]);
      *(us4*)(&Pl[w][0] + lam*144 + mt*32 + lg*8) = pk;
    }
    // rescale O accumulator
    float fr[4];
    #pragma unroll
    for (int r=0;r<4;++r) fr[r] = __shfl(fs, 4*lg + r);
    #pragma unroll
    for (int i=0;i<16;++i){
      #pragma unroll
      for (int r=0;r<4;++r) oa[i][r] *= fr[r];
    }
    // PV
    #pragma unroll
    for (int ks=0;ks<2;++ks){
      s16x8 pa = *(const s16x8*)(&Pl[w][0] + lam*144 + ks*64 + lg*16);
      #pragma unroll
      for (int ct=0;ct<16;++ct){
        int c = lam + 16*ct;
        s16x8 vf = *(const s16x8*)((const char*)Vl + c*128 + ((ks*64 + 16*lg) ^ ((c&7)<<4)));
        oa[ct] = MFMA16(pa, vf, oa[ct]);
      }
    }
  }
  // epilogue: normalize, write AOt[n][c]
  float li = 1.f/l_run;
  float lr[4];
  #pragma unroll
  for (int r=0;r<4;++r) lr[r] = __shfl(li, 4*lg + r);
  #pragma unroll
  for (int ct=0;ct<16;++ct){
    #pragma unroll
    for (int r=0;r<4;++r){
      AOt[((size_t)(b*4096 + qbase + 4*lg + r))*256 + lam + 16*ct] = f2b(oa[ct][r]*lr[r]);
    }
  }
}

// ---------------- OUT GEMM: out[o][n] = AOt[n][c]*out_w[o][c]^T + bias + x (f32 out) ----------------
__global__ __launch_bounds__(256,2) void k_gemm_out(const unsigned short* __restrict__ Ag,
    const unsigned short* __restrict__ Bg, const float* __restrict__ biasg,
    const float* __restrict__ xg, float* __restrict__ outg){
  __shared__ unsigned short Al[64*256], Bl[64*256];
  const int at = blockIdx.x, bt = blockIdx.y, b = blockIdx.z;
  const int a0 = at*64, o0 = bt*64;
  stage_64x256(Al, Ag + ((size_t)(b*4096 + a0))*256, 256);
  stage_64x256(Bl, Bg + (size_t)o0*256, 256);
  __syncthreads();
  const int t = threadIdx.x, w = t>>6, lane = t&63, lam = lane&15, lg = lane>>4;
  f32x4 zz = {0.f,0.f,0.f,0.f};
  f32x4 acc[4] = {zz,zz,zz,zz};
  #pragma unroll
  for (int u=0;u<8;++u){
    int ar = 16*w + lam;
    s16x8 af = *(const s16x8*)((const char*)Al + ar*512 + ((64*u+16*lg) ^ ((ar&7)<<4)));
    #pragma unroll
    for (int ct=0;ct<4;++ct){
      int br = 16*ct + lam;
      s16x8 bf = *(const s16x8*)((const char*)Bl + br*512 + ((64*u+16*lg) ^ ((br&7)<<4)));
      acc[ct] = MFMA16(af, bf, acc[ct]);
    }
  }
  #pragma unroll
  for (int ct=0;ct<4;++ct){
    int o = o0 + 16*ct + lam;
    float ob_ = biasg[o];
    size_t base = ((size_t)(b*256 + o))*4096 + a0 + 16*w + 4*lg;
    f32x4 xv = *(const f32x4*)(xg + base);
    f32x4 ov;
    #pragma unroll
    for (int r=0;r<4;++r) ov[r] = acc[ct][r] + ob_ + xv[r];
    *(f32x4*)(outg + base) = ov;
  }
}

extern "C" void kernel_launch(void* const* d_in, const int* in_sizes, int n_in,
                              void* d_out, int out_size, void* d_ws, size_t ws_size,
                              hipStream_t stream){
  const float* x     = (const float*)d_in[0];
  const float* qkv_w = (const float*)d_in[1];
  const float* qkv_b = (const float*)d_in[2];
  const float* out_w = (const float*)d_in[3];
  const float* out_b = (const float*)d_in[4];
  const float* d1_w  = (const float*)d_in[5];
  const float* d1_b  = (const float*)d_in[6];
  const float* d2_w  = (const float*)d_in[7];
  const float* d2_b  = (const float*)d_in[8];
  float* out = (float*)d_out;

  char* p = (char*)d_ws;
  const size_t BIG = (size_t)8*4096*256*2;
  unsigned short* Xt = (unsigned short*)p; p += BIG;   // reused as AOt after QKV GEMM
  unsigned short* Q  = (unsigned short*)p; p += BIG;
  unsigned short* K  = (unsigned short*)p; p += BIG;
  unsigned short* Vt = (unsigned short*)p; p += BIG;
  unsigned short* Wq = (unsigned short*)p; p += (size_t)768*256*2;
  unsigned short* Wo = (unsigned short*)p; p += (size_t)256*256*2;
  float* gray = (float*)p; p += (size_t)8*4096*4;
  float* labs = (float*)p; p += (size_t)8*4096*4;
  float* hbuf = (float*)p; p += (size_t)8*8*4096*4;
  float* sc   = (float*)p; p += (size_t)8*4096*4;

  k_cvt      <<<dim3(192),    256, 0, stream>>>(qkv_w, Wq);
  k_cvt      <<<dim3(64),     256, 0, stream>>>(out_w, Wo);
  k_transpose<<<dim3(64,4,8), 256, 0, stream>>>(x, Xt);
  k_gray     <<<dim3(16,8),   256, 0, stream>>>(x, gray);
  k_lapabs   <<<dim3(16,8),   256, 0, stream>>>(gray, labs);
  k_h8       <<<dim3(16,8),   256, 0, stream>>>(labs, d1_w, d1_b, hbuf);
  k_scale    <<<dim3(16,8),   256, 0, stream>>>(hbuf, d2_w, d2_b, sc);
  k_gemm_qkv <<<dim3(64,12,8),256, 0, stream>>>(Wq, Xt, qkv_b, Q, K, Vt);
  k_attn     <<<dim3(512),    256, 0, stream>>>(Q, K, Vt, sc, Xt);
  k_gemm_out <<<dim3(64,4,8), 256, 0, stream>>>(Xt, Wo, out_b, x, out);
}